// Round 18
// baseline (197.701 us; speedup 1.0000x reference)
//
#include <hip/hip_runtime.h>

typedef unsigned short ushort_t;
using frag_ab = __attribute__((ext_vector_type(8))) short;
using f32x4   = __attribute__((ext_vector_type(4))) float;
using u32x4   = __attribute__((ext_vector_type(4))) unsigned int;
using u32x2   = __attribute__((ext_vector_type(2))) unsigned int;

#define FDIM 512
#define NH 8
#define FATT 64
#define NX 2048
#define NP 4096
#define NTOT 6144

__device__ __forceinline__ ushort_t f2bf(float f) {
    unsigned u = __float_as_uint(f);
    u = (u + 0x7FFFu + ((u >> 16) & 1u)) >> 16;   // RTNE
    return (ushort_t)u;
}
__device__ __forceinline__ float bf2f(ushort_t s) {
    return __uint_as_float(((unsigned)s) << 16);
}
__device__ __forceinline__ unsigned pk2bf(float a, float b) {
    return (unsigned)f2bf(a) | ((unsigned)f2bf(b) << 16);
}

// ---------------------------------------------------------------------------
// K0: fp32 -> bf16 conversions: f = concat(fx, fp0), Wembd, Wfc, Wout
// ---------------------------------------------------------------------------
__global__ __launch_bounds__(256) void k_prep(const float* __restrict__ fx,
                                              const float* __restrict__ fp,
                                              const float* __restrict__ We,
                                              const float* __restrict__ Wfc,
                                              const float* __restrict__ Wout,
                                              ushort_t* __restrict__ f_b,
                                              ushort_t* __restrict__ We_b,
                                              ushort_t* __restrict__ Wfc_b,
                                              ushort_t* __restrict__ Wout_b) {
    int i = blockIdx.x * 256 + threadIdx.x;
    int stride = gridDim.x * 256;
    const int NF4 = NTOT * FDIM / 4;
    const int NX4 = NX * FDIM / 4;
    for (int idx = i; idx < NF4; idx += stride) {
        float4 v = (idx < NX4) ? ((const float4*)fx)[idx]
                               : ((const float4*)fp)[idx - NX4];
        ushort4 o;
        o.x = f2bf(v.x); o.y = f2bf(v.y); o.z = f2bf(v.z); o.w = f2bf(v.w);
        ((ushort4*)f_b)[idx] = o;
    }
    const int NW4 = FDIM * FDIM / 4;
    for (int idx = i; idx < NW4; idx += stride) {
        float4 v = ((const float4*)We)[idx];
        ushort4 o;
        o.x = f2bf(v.x); o.y = f2bf(v.y); o.z = f2bf(v.z); o.w = f2bf(v.w);
        ((ushort4*)We_b)[idx] = o;
    }
    const int NFC4 = NH * FATT * 2 * FATT / 4;
    for (int idx = i; idx < NFC4; idx += stride) {
        float4 v = ((const float4*)Wfc)[idx];
        ushort4 o;
        o.x = f2bf(v.x); o.y = f2bf(v.y); o.z = f2bf(v.z); o.w = f2bf(v.w);
        ((ushort4*)Wfc_b)[idx] = o;
    }
    for (int idx = i; idx < NW4; idx += stride) {
        float4 v = ((const float4*)Wout)[idx];
        ushort4 o;
        o.x = f2bf(v.x); o.y = f2bf(v.y); o.z = f2bf(v.z); o.w = f2bf(v.w);
        ((ushort4*)Wout_b)[idx] = o;
    }
}

// ---------------------------------------------------------------------------
// K1: femb[h][n][e] = f[n] . Wembd[h][e] + bembd  (MFMA GEMM, bf16 out)
//     also writes fpT[h][e][p] (n>=NX) and facat[h][x][64+e] (n<NX)
// ---------------------------------------------------------------------------
__global__ __launch_bounds__(256) void k_embed(const ushort_t* __restrict__ f_b,
                                               const ushort_t* __restrict__ We_b,
                                               const float* __restrict__ bembd,
                                               ushort_t* __restrict__ femb_b,
                                               ushort_t* __restrict__ fpT_b,
                                               ushort_t* __restrict__ facat_b) {
    int tid = threadIdx.x;
    int wv = tid >> 6, lane = tid & 63;
    int g = lane >> 4, c = lane & 15;
    int m0 = blockIdx.x * 64 + wv * 16;
    int o0 = blockIdx.y * 64;

    f32x4 acc[4] = {};
    const ushort_t* arow = f_b + (size_t)(m0 + c) * FDIM + g * 8;
#pragma unroll 4
    for (int ks = 0; ks < FDIM; ks += 32) {
        frag_ab a = *(const frag_ab*)(arow + ks);
#pragma unroll
        for (int t = 0; t < 4; ++t) {
            const ushort_t* brow = We_b + (size_t)(o0 + t * 16 + c) * FDIM + ks + g * 8;
            frag_ab b = *(const frag_ab*)brow;
            acc[t] = __builtin_amdgcn_mfma_f32_16x16x32_bf16(a, b, acc[t], 0, 0, 0);
        }
    }
#pragma unroll
    for (int t = 0; t < 4; ++t) {
        int o = o0 + t * 16 + c;           // output feature = h*64+e
        int h = o >> 6, e = o & 63;
        float bia = bembd[o];
#pragma unroll
        for (int r = 0; r < 4; ++r) {
            int n = m0 + g * 4 + r;
            ushort_t v = f2bf(acc[t][r] + bia);
            femb_b[((size_t)h * NTOT + n) * FATT + e] = v;
            if (n >= NX) fpT_b[((size_t)h * FATT + e) * NP + (n - NX)] = v;
            else         facat_b[((size_t)h * NX + n) * 128 + 64 + e] = v;
        }
    }
}

// ---------------------------------------------------------------------------
// K2a: attention pass-1 — 1024 threads (16 waves, 4/SIMD), 64 x-rows/block,
//   wave owns a 256-p slice. K/V reads amortized over 64 x. Writes facat
//   bf16 + inv_sums.
// ---------------------------------------------------------------------------
__global__ __launch_bounds__(1024) void k_attn_p1(const ushort_t* __restrict__ femb_b,
                                                  const ushort_t* __restrict__ fpT_b,
                                                  float* __restrict__ inv_sums,
                                                  ushort_t* __restrict__ facat_b) {
    int bid = blockIdx.x;
    int h  = bid & 7;                 // head == XCD affinity
    int xb = bid >> 3;                // 0..31, x-base = xb*64
    int tid = threadIdx.x;
    int wv = tid >> 6;                // 0..15 -> 256-p slice
    int lane = tid & 63;
    int g = lane >> 4, c = lane & 15;

    __shared__ float lds_pv[64][68];  // combined PV [x_local][e], pad 68
    __shared__ float lds_sum[64];
    __shared__ float lds_inv[64];

    const ushort_t* fxb = femb_b + (size_t)h * NTOT * FATT;
    const ushort_t* fpb = fxb + (size_t)NX * FATT;
    const ushort_t* fTb = fpT_b + (size_t)h * FATT * NP;

    // Q B-frags for 4 x-groups
    frag_ab bx0_0, bx0_1, bx1_0, bx1_1, bx2_0, bx2_1, bx3_0, bx3_1;
    {
        const ushort_t* b0 = fxb + (size_t)(xb * 64 + 0 * 16 + c) * FATT + g * 8;
        const ushort_t* b1 = fxb + (size_t)(xb * 64 + 1 * 16 + c) * FATT + g * 8;
        const ushort_t* b2 = fxb + (size_t)(xb * 64 + 2 * 16 + c) * FATT + g * 8;
        const ushort_t* b3 = fxb + (size_t)(xb * 64 + 3 * 16 + c) * FATT + g * 8;
        bx0_0 = *(const frag_ab*)b0;  bx0_1 = *(const frag_ab*)(b0 + 32);
        bx1_0 = *(const frag_ab*)b1;  bx1_1 = *(const frag_ab*)(b1 + 32);
        bx2_0 = *(const frag_ab*)b2;  bx2_1 = *(const frag_ab*)(b2 + 32);
        bx3_0 = *(const frag_ab*)b3;  bx3_1 = *(const frag_ab*)(b3 + 32);
    }

    f32x4 pacc[4][4] = {};            // [xg][t2], static indices only
    float rsum[4] = {0.f, 0.f, 0.f, 0.f};
    const int p0 = wv * 256;

    for (int ps = p0; ps < p0 + 256; ps += 16) {
        const ushort_t* ar = fpb + (size_t)(ps + c) * FATT + g * 8;
        frag_ab a0 = *(const frag_ab*)ar;
        frag_ab a1 = *(const frag_ab*)(ar + 32);
        frag_ab pb[4];
#pragma unroll
        for (int xg = 0; xg < 4; ++xg) {
            frag_ab q0 = (xg == 0) ? bx0_0 : (xg == 1) ? bx1_0 : (xg == 2) ? bx2_0 : bx3_0;
            frag_ab q1 = (xg == 0) ? bx0_1 : (xg == 1) ? bx1_1 : (xg == 2) ? bx2_1 : bx3_1;
            f32x4 s = {};
            s = __builtin_amdgcn_mfma_f32_16x16x32_bf16(a0, q0, s, 0, 0, 0);
            s = __builtin_amdgcn_mfma_f32_16x16x32_bf16(a1, q1, s, 0, 0, 0);
            float e0 = __expf(s[0] * 0.125f);
            float e1 = __expf(s[1] * 0.125f);
            float e2 = __expf(s[2] * 0.125f);
            float e3 = __expf(s[3] * 0.125f);
            rsum[xg] += (e0 + e1) + (e2 + e3);
            u32x4 bw;
            bw[0] = pk2bf(e0, e1);
            bw[1] = pk2bf(e2, e3);
            bw[2] = 0u;
            bw[3] = 0u;
            pb[xg] = __builtin_bit_cast(frag_ab, bw);
        }
#pragma unroll
        for (int t2 = 0; t2 < 4; ++t2) {
            const ushort_t* vr = fTb + (size_t)(t2 * 16 + c) * NP + ps + g * 4;
            u32x2 vl = *(const u32x2*)vr;
            u32x4 aw;
            aw[0] = vl[0];
            aw[1] = vl[1];
            aw[2] = 0u;
            aw[3] = 0u;
            frag_ab va = __builtin_bit_cast(frag_ab, aw);
#pragma unroll
            for (int xg = 0; xg < 4; ++xg)
                pacc[xg][t2] = __builtin_amdgcn_mfma_f32_16x16x32_bf16(va, pb[xg], pacc[xg][t2], 0, 0, 0);
        }
    }

#pragma unroll
    for (int xg = 0; xg < 4; ++xg) {
        rsum[xg] += __shfl_xor(rsum[xg], 16);
        rsum[xg] += __shfl_xor(rsum[xg], 32);
    }

    // cross-wave combine: 16 serialized accumulation rounds
    for (int w = 0; w < 16; ++w) {
        if (wv == w) {
            if (w == 0) {
                if (lane < 16) {
#pragma unroll
                    for (int xg = 0; xg < 4; ++xg) lds_sum[xg * 16 + c] = rsum[xg];
                }
#pragma unroll
                for (int xg = 0; xg < 4; ++xg)
#pragma unroll
                    for (int t2 = 0; t2 < 4; ++t2)
                        *(f32x4*)&lds_pv[xg * 16 + c][t2 * 16 + 4 * g] = pacc[xg][t2];
            } else {
                if (lane < 16) {
#pragma unroll
                    for (int xg = 0; xg < 4; ++xg) lds_sum[xg * 16 + c] += rsum[xg];
                }
#pragma unroll
                for (int xg = 0; xg < 4; ++xg)
#pragma unroll
                    for (int t2 = 0; t2 < 4; ++t2) {
                        f32x4 cur = *(const f32x4*)&lds_pv[xg * 16 + c][t2 * 16 + 4 * g];
                        cur += pacc[xg][t2];
                        *(f32x4*)&lds_pv[xg * 16 + c][t2 * 16 + 4 * g] = cur;
                    }
            }
        }
        __syncthreads();
    }
    if (tid < 64) {
        float inv = 1.f / lds_sum[tid];
        lds_inv[tid] = inv;
        inv_sums[(size_t)h * NX + xb * 64 + tid] = inv;
    }
    __syncthreads();

    // facat write: 512 threads x 8 elems = 64 x-rows x 64 e
    if (tid < 512) {
        int row = tid >> 3;
        int e0 = (tid & 7) * 8;
        float inv = lds_inv[row];
        u32x4 o;
#pragma unroll
        for (int j = 0; j < 4; ++j)
            o[j] = pk2bf(lds_pv[row][e0 + 2 * j] * inv, lds_pv[row][e0 + 2 * j + 1] * inv);
        *(u32x4*)&facat_b[((size_t)h * NX + xb * 64 + row) * 128 + e0] = o;
    }
}

// ---------------------------------------------------------------------------
// K2b: w_out writer v2 — 64-x READ AMORTIZATION: each wave holds the 8
//   A-fragment pairs of a 128-p chunk in REGISTERS (read once) and reuses
//   them for 4 Q-groups (64 x). Wave-private LDS transpose (no barriers),
//   contiguous 512B row stores. Grid 1024 = 8h x 32xb x 4sl; 4 waves/block,
//   wave owns 256 p.
// ---------------------------------------------------------------------------
__global__ __launch_bounds__(256) void k_wout(const ushort_t* __restrict__ femb_b,
                                              const float* __restrict__ inv_sums,
                                              float* __restrict__ w_out) {
    int bid = blockIdx.x;
    int h    = bid & 7;
    int rest = bid >> 3;               // 0..127
    int xb   = rest & 31;              // 64-x group
    int sl   = rest >> 5;              // 0..3 -> 1024-p slice
    int tid = threadIdx.x;
    int wv = tid >> 6;                 // 0..3 -> 256-p sub-slice
    int lane = tid & 63;
    int g = lane >> 4, c = lane & 15;

    __shared__ float lds[4][16][132];  // per-wave 16 x-rows x 128 p (pad 4)

    const ushort_t* fxb = femb_b + (size_t)h * NTOT * FATT;
    const ushort_t* fpb = fxb + (size_t)NX * FATT;

    // Q frags + inv for 4 x-groups
    frag_ab q0[4], q1[4];
    float inv[4];
#pragma unroll
    for (int xg = 0; xg < 4; ++xg) {
        const ushort_t* b = fxb + (size_t)(xb * 64 + xg * 16 + c) * FATT + g * 8;
        q0[xg] = *(const frag_ab*)b;
        q1[xg] = *(const frag_ab*)(b + 32);
        inv[xg] = inv_sums[(size_t)h * NX + xb * 64 + xg * 16 + c];
    }

    const int p_base = sl * 1024 + wv * 256;
    for (int chunk = 0; chunk < 2; ++chunk) {
        int pc = p_base + chunk * 128;
        // read the chunk's 8 A-fragment pairs ONCE into registers
        frag_ab af0[8], af1[8];
#pragma unroll
        for (int pt = 0; pt < 8; ++pt) {
            const ushort_t* ar = fpb + (size_t)(pc + pt * 16 + c) * FATT + g * 8;
            af0[pt] = *(const frag_ab*)ar;
            af1[pt] = *(const frag_ab*)(ar + 32);
        }
#pragma unroll
        for (int xg = 0; xg < 4; ++xg) {
#pragma unroll
            for (int pt = 0; pt < 8; ++pt) {
                f32x4 s = {};
                s = __builtin_amdgcn_mfma_f32_16x16x32_bf16(af0[pt], q0[xg], s, 0, 0, 0);
                s = __builtin_amdgcn_mfma_f32_16x16x32_bf16(af1[pt], q1[xg], s, 0, 0, 0);
                // lane holds w for p = pc + pt*16 + 4g + r, x = xg*16 + c
                f32x4 ev;
                ev[0] = __expf(s[0] * 0.125f) * inv[xg];
                ev[1] = __expf(s[1] * 0.125f) * inv[xg];
                ev[2] = __expf(s[2] * 0.125f) * inv[xg];
                ev[3] = __expf(s[3] * 0.125f) * inv[xg];
                int sw = (pt * 16 + g * 4) ^ ((c & 7) << 4);   // validated swizzle
                *(f32x4*)&lds[wv][c][sw] = ev;
            }
            // contiguous row writes: 64 lanes x float2 = 512B per instruction
#pragma unroll
            for (int row = 0; row < 16; ++row) {
                int pi = lane * 2;
                int swr = pi ^ ((row & 7) << 4);
                float2 v = *(const float2*)&lds[wv][row][swr];
                float* dst = w_out + ((size_t)(xb * 64 + xg * 16 + row) * NH + h) * NP + pc + pi;
                *(float2*)dst = v;
            }
        }
    }
}

// ---------------------------------------------------------------------------
// K3: fc — per-head MFMA GEMM (2048 x 64out x 128k), relu, bf16 out
// ---------------------------------------------------------------------------
__global__ __launch_bounds__(256) void k_fc(const ushort_t* __restrict__ facat_b,
                                            const ushort_t* __restrict__ Wfc_b,
                                            const float* __restrict__ bfc,
                                            ushort_t* __restrict__ fcout_b) {
    int tid = threadIdx.x;
    int wv = tid >> 6, lane = tid & 63;
    int g = lane >> 4, c = lane & 15;
    int x0 = blockIdx.x * 64 + wv * 16;
    int h = blockIdx.y;

    const ushort_t* A = facat_b + ((size_t)h * NX + x0 + c) * 128 + g * 8;
    const ushort_t* B = Wfc_b + (size_t)h * FATT * 128;

    f32x4 acc[4] = {};
#pragma unroll
    for (int ks = 0; ks < 128; ks += 32) {
        frag_ab a = *(const frag_ab*)(A + ks);
#pragma unroll
        for (int t = 0; t < 4; ++t) {
            frag_ab b = *(const frag_ab*)(B + (size_t)(t * 16 + c) * 128 + ks + g * 8);
            acc[t] = __builtin_amdgcn_mfma_f32_16x16x32_bf16(a, b, acc[t], 0, 0, 0);
        }
    }
#pragma unroll
    for (int t = 0; t < 4; ++t) {
        int e = t * 16 + c;
        float bia = bfc[h * FATT + e];
#pragma unroll
        for (int r = 0; r < 4; ++r) {
            int x = x0 + g * 4 + r;
            fcout_b[(size_t)x * FDIM + h * FATT + e] = f2bf(fmaxf(acc[t][r] + bia, 0.f));
        }
    }
}

// ---------------------------------------------------------------------------
// K4: out GEMM (2048 x 512 x 512) MFMA + residual + bias + relu (fp32 out)
// ---------------------------------------------------------------------------
__global__ __launch_bounds__(256) void k_out(const float* __restrict__ fx_in,
                                             const ushort_t* __restrict__ fcout_b,
                                             const ushort_t* __restrict__ Wout_b,
                                             const float* __restrict__ bout,
                                             float* __restrict__ out) {
    int tid = threadIdx.x;
    int wv = tid >> 6, lane = tid & 63;
    int g = lane >> 4, c = lane & 15;
    int x0 = blockIdx.x * 64 + wv * 16;
    int o0 = blockIdx.y * 64;

    f32x4 acc[4] = {};
    const ushort_t* A = fcout_b + (size_t)(x0 + c) * FDIM + g * 8;
#pragma unroll 4
    for (int ks = 0; ks < FDIM; ks += 32) {
        frag_ab a = *(const frag_ab*)(A + ks);
#pragma unroll
        for (int t = 0; t < 4; ++t) {
            frag_ab b = *(const frag_ab*)(Wout_b + (size_t)(o0 + t * 16 + c) * FDIM + ks + g * 8);
            acc[t] = __builtin_amdgcn_mfma_f32_16x16x32_bf16(a, b, acc[t], 0, 0, 0);
        }
    }
#pragma unroll
    for (int t = 0; t < 4; ++t) {
        int f = o0 + t * 16 + c;
        float bia = bout[f];
#pragma unroll
        for (int r = 0; r < 4; ++r) {
            int x = x0 + g * 4 + r;
            float v = acc[t][r] + bia + fx_in[(size_t)x * FDIM + f];
            out[(size_t)x * FDIM + f] = fmaxf(v, 0.f);
        }
    }
}

extern "C" void kernel_launch(void* const* d_in, const int* in_sizes, int n_in,
                              void* d_out, int out_size, void* d_ws, size_t ws_size,
                              hipStream_t stream) {
    const float* fx_in = (const float*)d_in[0];
    const float* fp_in = (const float*)d_in[1];
    const float* Wembd = (const float*)d_in[2];
    const float* bembd = (const float*)d_in[3];
    const float* Wfc   = (const float*)d_in[4];
    const float* bfc   = (const float*)d_in[5];
    const float* Wout  = (const float*)d_in[6];
    const float* bout  = (const float*)d_in[7];

    float* out   = (float*)d_out;
    float* w_out = out + (size_t)NX * FDIM;

    ushort_t* f_b     = (ushort_t*)d_ws;                     // 6144*512
    ushort_t* We_b    = f_b + (size_t)NTOT * FDIM;           // 512*512
    ushort_t* femb_b  = We_b + (size_t)FDIM * FDIM;          // 8*6144*64
    ushort_t* fpT_b   = femb_b + (size_t)NH * NTOT * FATT;   // 8*64*4096
    ushort_t* facat_b = fpT_b + (size_t)NH * FATT * NP;      // 8*2048*128
    ushort_t* fcout_b = facat_b + (size_t)NH * NX * 128;     // 2048*512
    ushort_t* Wfc_b   = fcout_b + (size_t)NX * FDIM;         // 8*64*128
    ushort_t* Wout_b  = Wfc_b + (size_t)NH * FATT * 2 * FATT;// 512*512
    float*    inv_sums= (float*)(Wout_b + (size_t)FDIM * FDIM); // 8*2048 f32

    k_prep   <<<1024, 256, 0, stream>>>(fx_in, fp_in, Wembd, Wfc, Wout,
                                        f_b, We_b, Wfc_b, Wout_b);
    k_embed  <<<dim3(96, 8), 256, 0, stream>>>(f_b, We_b, bembd, femb_b, fpT_b, facat_b);
    k_attn_p1<<<256, 1024, 0, stream>>>(femb_b, fpT_b, inv_sums, facat_b);
    k_wout   <<<1024, 256, 0, stream>>>(femb_b, inv_sums, w_out);
    k_fc     <<<dim3(32, 8), 256, 0, stream>>>(facat_b, Wfc_b, bfc, fcout_b);
    k_out    <<<dim3(32, 8), 256, 0, stream>>>(fx_in, fcout_b, Wout_b, bout, out);
}

// Round 19
// 179.240 us; speedup vs baseline: 1.1030x; 1.1030x over previous
//
#include <hip/hip_runtime.h>

typedef unsigned short ushort_t;
using frag_ab = __attribute__((ext_vector_type(8))) short;
using f32x4   = __attribute__((ext_vector_type(4))) float;
using u32x4   = __attribute__((ext_vector_type(4))) unsigned int;
using u32x2   = __attribute__((ext_vector_type(2))) unsigned int;

#define FDIM 512
#define NH 8
#define FATT 64
#define NX 2048
#define NP 4096
#define NTOT 6144

__device__ __forceinline__ ushort_t f2bf(float f) {
    unsigned u = __float_as_uint(f);
    u = (u + 0x7FFFu + ((u >> 16) & 1u)) >> 16;   // RTNE
    return (ushort_t)u;
}
__device__ __forceinline__ float bf2f(ushort_t s) {
    return __uint_as_float(((unsigned)s) << 16);
}
__device__ __forceinline__ unsigned pk2bf(float a, float b) {
    return (unsigned)f2bf(a) | ((unsigned)f2bf(b) << 16);
}

// ---------------------------------------------------------------------------
// K0: fp32 -> bf16 conversions: f = concat(fx, fp0), Wembd, Wfc, Wout
// ---------------------------------------------------------------------------
__global__ __launch_bounds__(256) void k_prep(const float* __restrict__ fx,
                                              const float* __restrict__ fp,
                                              const float* __restrict__ We,
                                              const float* __restrict__ Wfc,
                                              const float* __restrict__ Wout,
                                              ushort_t* __restrict__ f_b,
                                              ushort_t* __restrict__ We_b,
                                              ushort_t* __restrict__ Wfc_b,
                                              ushort_t* __restrict__ Wout_b) {
    int i = blockIdx.x * 256 + threadIdx.x;
    int stride = gridDim.x * 256;
    const int NF4 = NTOT * FDIM / 4;
    const int NX4 = NX * FDIM / 4;
    for (int idx = i; idx < NF4; idx += stride) {
        float4 v = (idx < NX4) ? ((const float4*)fx)[idx]
                               : ((const float4*)fp)[idx - NX4];
        ushort4 o;
        o.x = f2bf(v.x); o.y = f2bf(v.y); o.z = f2bf(v.z); o.w = f2bf(v.w);
        ((ushort4*)f_b)[idx] = o;
    }
    const int NW4 = FDIM * FDIM / 4;
    for (int idx = i; idx < NW4; idx += stride) {
        float4 v = ((const float4*)We)[idx];
        ushort4 o;
        o.x = f2bf(v.x); o.y = f2bf(v.y); o.z = f2bf(v.z); o.w = f2bf(v.w);
        ((ushort4*)We_b)[idx] = o;
    }
    const int NFC4 = NH * FATT * 2 * FATT / 4;
    for (int idx = i; idx < NFC4; idx += stride) {
        float4 v = ((const float4*)Wfc)[idx];
        ushort4 o;
        o.x = f2bf(v.x); o.y = f2bf(v.y); o.z = f2bf(v.z); o.w = f2bf(v.w);
        ((ushort4*)Wfc_b)[idx] = o;
    }
    for (int idx = i; idx < NW4; idx += stride) {
        float4 v = ((const float4*)Wout)[idx];
        ushort4 o;
        o.x = f2bf(v.x); o.y = f2bf(v.y); o.z = f2bf(v.z); o.w = f2bf(v.w);
        ((ushort4*)Wout_b)[idx] = o;
    }
}

// ---------------------------------------------------------------------------
// K1: femb[h][n][e] = f[n] . Wembd[h][e] + bembd  (MFMA GEMM, bf16 out)
//     also writes fpT[h][e][p] (n>=NX) and facat[h][x][64+e] (n<NX)
// ---------------------------------------------------------------------------
__global__ __launch_bounds__(256) void k_embed(const ushort_t* __restrict__ f_b,
                                               const ushort_t* __restrict__ We_b,
                                               const float* __restrict__ bembd,
                                               ushort_t* __restrict__ femb_b,
                                               ushort_t* __restrict__ fpT_b,
                                               ushort_t* __restrict__ facat_b) {
    int tid = threadIdx.x;
    int wv = tid >> 6, lane = tid & 63;
    int g = lane >> 4, c = lane & 15;
    int m0 = blockIdx.x * 64 + wv * 16;
    int o0 = blockIdx.y * 64;

    f32x4 acc[4] = {};
    const ushort_t* arow = f_b + (size_t)(m0 + c) * FDIM + g * 8;
#pragma unroll 4
    for (int ks = 0; ks < FDIM; ks += 32) {
        frag_ab a = *(const frag_ab*)(arow + ks);
#pragma unroll
        for (int t = 0; t < 4; ++t) {
            const ushort_t* brow = We_b + (size_t)(o0 + t * 16 + c) * FDIM + ks + g * 8;
            frag_ab b = *(const frag_ab*)brow;
            acc[t] = __builtin_amdgcn_mfma_f32_16x16x32_bf16(a, b, acc[t], 0, 0, 0);
        }
    }
#pragma unroll
    for (int t = 0; t < 4; ++t) {
        int o = o0 + t * 16 + c;           // output feature = h*64+e
        int h = o >> 6, e = o & 63;
        float bia = bembd[o];
#pragma unroll
        for (int r = 0; r < 4; ++r) {
            int n = m0 + g * 4 + r;
            ushort_t v = f2bf(acc[t][r] + bia);
            femb_b[((size_t)h * NTOT + n) * FATT + e] = v;
            if (n >= NX) fpT_b[((size_t)h * FATT + e) * NP + (n - NX)] = v;
            else         facat_b[((size_t)h * NX + n) * 128 + 64 + e] = v;
        }
    }
}

// ---------------------------------------------------------------------------
// K2a: attention pass-1 (round-17 validated best) — 512 threads (8 waves),
//   64 x-rows/block, wave owns a 512-p slice. K/V reads amortized over 64 x.
//   Writes facat bf16 + inv_sums.
// ---------------------------------------------------------------------------
__global__ __launch_bounds__(512) void k_attn_p1(const ushort_t* __restrict__ femb_b,
                                                 const ushort_t* __restrict__ fpT_b,
                                                 float* __restrict__ inv_sums,
                                                 ushort_t* __restrict__ facat_b) {
    int bid = blockIdx.x;
    int h  = bid & 7;                 // head == XCD affinity
    int xb = bid >> 3;                // 0..31, x-base = xb*64
    int tid = threadIdx.x;
    int wv = tid >> 6;                // 0..7 -> 512-p slice
    int lane = tid & 63;
    int g = lane >> 4, c = lane & 15;

    __shared__ float lds_pv[64][68];  // combined PV [x_local][e], pad 68
    __shared__ float lds_sum[64];
    __shared__ float lds_inv[64];

    const ushort_t* fxb = femb_b + (size_t)h * NTOT * FATT;
    const ushort_t* fpb = fxb + (size_t)NX * FATT;
    const ushort_t* fTb = fpT_b + (size_t)h * FATT * NP;

    // Q B-frags for 4 x-groups
    frag_ab bx0_0, bx0_1, bx1_0, bx1_1, bx2_0, bx2_1, bx3_0, bx3_1;
    {
        const ushort_t* b0 = fxb + (size_t)(xb * 64 + 0 * 16 + c) * FATT + g * 8;
        const ushort_t* b1 = fxb + (size_t)(xb * 64 + 1 * 16 + c) * FATT + g * 8;
        const ushort_t* b2 = fxb + (size_t)(xb * 64 + 2 * 16 + c) * FATT + g * 8;
        const ushort_t* b3 = fxb + (size_t)(xb * 64 + 3 * 16 + c) * FATT + g * 8;
        bx0_0 = *(const frag_ab*)b0;  bx0_1 = *(const frag_ab*)(b0 + 32);
        bx1_0 = *(const frag_ab*)b1;  bx1_1 = *(const frag_ab*)(b1 + 32);
        bx2_0 = *(const frag_ab*)b2;  bx2_1 = *(const frag_ab*)(b2 + 32);
        bx3_0 = *(const frag_ab*)b3;  bx3_1 = *(const frag_ab*)(b3 + 32);
    }

    f32x4 pacc[4][4] = {};            // [xg][t2], static indices only
    float rsum[4] = {0.f, 0.f, 0.f, 0.f};
    const int p0 = wv * 512;

    for (int ps = p0; ps < p0 + 512; ps += 16) {
        const ushort_t* ar = fpb + (size_t)(ps + c) * FATT + g * 8;
        frag_ab a0 = *(const frag_ab*)ar;
        frag_ab a1 = *(const frag_ab*)(ar + 32);
        frag_ab pb[4];
#pragma unroll
        for (int xg = 0; xg < 4; ++xg) {
            frag_ab q0 = (xg == 0) ? bx0_0 : (xg == 1) ? bx1_0 : (xg == 2) ? bx2_0 : bx3_0;
            frag_ab q1 = (xg == 0) ? bx0_1 : (xg == 1) ? bx1_1 : (xg == 2) ? bx2_1 : bx3_1;
            f32x4 s = {};
            s = __builtin_amdgcn_mfma_f32_16x16x32_bf16(a0, q0, s, 0, 0, 0);
            s = __builtin_amdgcn_mfma_f32_16x16x32_bf16(a1, q1, s, 0, 0, 0);
            float e0 = __expf(s[0] * 0.125f);
            float e1 = __expf(s[1] * 0.125f);
            float e2 = __expf(s[2] * 0.125f);
            float e3 = __expf(s[3] * 0.125f);
            rsum[xg] += (e0 + e1) + (e2 + e3);
            u32x4 bw;
            bw[0] = pk2bf(e0, e1);
            bw[1] = pk2bf(e2, e3);
            bw[2] = 0u;
            bw[3] = 0u;
            pb[xg] = __builtin_bit_cast(frag_ab, bw);
        }
#pragma unroll
        for (int t2 = 0; t2 < 4; ++t2) {
            const ushort_t* vr = fTb + (size_t)(t2 * 16 + c) * NP + ps + g * 4;
            u32x2 vl = *(const u32x2*)vr;
            u32x4 aw;
            aw[0] = vl[0];
            aw[1] = vl[1];
            aw[2] = 0u;
            aw[3] = 0u;
            frag_ab va = __builtin_bit_cast(frag_ab, aw);
#pragma unroll
            for (int xg = 0; xg < 4; ++xg)
                pacc[xg][t2] = __builtin_amdgcn_mfma_f32_16x16x32_bf16(va, pb[xg], pacc[xg][t2], 0, 0, 0);
        }
    }

#pragma unroll
    for (int xg = 0; xg < 4; ++xg) {
        rsum[xg] += __shfl_xor(rsum[xg], 16);
        rsum[xg] += __shfl_xor(rsum[xg], 32);
    }

    // cross-wave combine: 8 serialized accumulation rounds
    for (int w = 0; w < 8; ++w) {
        if (wv == w) {
            if (w == 0) {
                if (lane < 16) {
#pragma unroll
                    for (int xg = 0; xg < 4; ++xg) lds_sum[xg * 16 + c] = rsum[xg];
                }
#pragma unroll
                for (int xg = 0; xg < 4; ++xg)
#pragma unroll
                    for (int t2 = 0; t2 < 4; ++t2)
                        *(f32x4*)&lds_pv[xg * 16 + c][t2 * 16 + 4 * g] = pacc[xg][t2];
            } else {
                if (lane < 16) {
#pragma unroll
                    for (int xg = 0; xg < 4; ++xg) lds_sum[xg * 16 + c] += rsum[xg];
                }
#pragma unroll
                for (int xg = 0; xg < 4; ++xg)
#pragma unroll
                    for (int t2 = 0; t2 < 4; ++t2) {
                        f32x4 cur = *(const f32x4*)&lds_pv[xg * 16 + c][t2 * 16 + 4 * g];
                        cur += pacc[xg][t2];
                        *(f32x4*)&lds_pv[xg * 16 + c][t2 * 16 + 4 * g] = cur;
                    }
            }
        }
        __syncthreads();
    }
    if (tid < 64) {
        float inv = 1.f / lds_sum[tid];
        lds_inv[tid] = inv;
        inv_sums[(size_t)h * NX + xb * 64 + tid] = inv;
    }
    __syncthreads();

    // facat write: 512 threads x 8 elems = 64 x-rows x 64 e
    {
        int row = tid >> 3;
        int e0 = (tid & 7) * 8;
        float inv = lds_inv[row];
        u32x4 o;
#pragma unroll
        for (int j = 0; j < 4; ++j)
            o[j] = pk2bf(lds_pv[row][e0 + 2 * j] * inv, lds_pv[row][e0 + 2 * j + 1] * inv);
        *(u32x4*)&facat_b[((size_t)h * NX + xb * 64 + row) * 128 + e0] = o;
    }
}

// ---------------------------------------------------------------------------
// K2b: w_out writer v3 — NO LDS, NO barriers, 4x read amortization with
//   pt-outer/xg-inner (transient A registers). Swapped-QK D layout gives
//   each lane 4 CONSECUTIVE p for one x-row -> direct f32x4 stores
//   (1 KB/instruction per wave). Grid 2048 = 8h x 32xb x 8sl; 4 waves,
//   wave owns 64 x times 128 p.
// ---------------------------------------------------------------------------
__global__ __launch_bounds__(256) void k_wout(const ushort_t* __restrict__ femb_b,
                                              const float* __restrict__ inv_sums,
                                              float* __restrict__ w_out) {
    int bid = blockIdx.x;
    int h    = bid & 7;
    int rest = bid >> 3;               // 0..255
    int xb   = rest & 31;              // 64-x group
    int sl   = rest >> 5;              // 0..7 -> 512-p slice
    int tid = threadIdx.x;
    int wv = tid >> 6;                 // 0..3 -> 128-p sub-slice
    int lane = tid & 63;
    int g = lane >> 4, c = lane & 15;

    const ushort_t* fxb = femb_b + (size_t)h * NTOT * FATT;
    const ushort_t* fpb = fxb + (size_t)NX * FATT;

    // Q frags + inv for 4 x-groups (x = xb*64 + xg*16 + c)
    frag_ab q0[4], q1[4];
    float inv[4];
#pragma unroll
    for (int xg = 0; xg < 4; ++xg) {
        const ushort_t* b = fxb + (size_t)(xb * 64 + xg * 16 + c) * FATT + g * 8;
        q0[xg] = *(const frag_ab*)b;
        q1[xg] = *(const frag_ab*)(b + 32);
        inv[xg] = inv_sums[(size_t)h * NX + xb * 64 + xg * 16 + c];
    }

    const int p0 = sl * 512 + wv * 128;
    for (int ps = p0; ps < p0 + 128; ps += 16) {
        // read the A-fragment pair ONCE, reuse for 4 x-groups
        const ushort_t* ar = fpb + (size_t)(ps + c) * FATT + g * 8;
        frag_ab a0 = *(const frag_ab*)ar;
        frag_ab a1 = *(const frag_ab*)(ar + 32);
#pragma unroll
        for (int xg = 0; xg < 4; ++xg) {
            f32x4 s = {};
            s = __builtin_amdgcn_mfma_f32_16x16x32_bf16(a0, q0[xg], s, 0, 0, 0);
            s = __builtin_amdgcn_mfma_f32_16x16x32_bf16(a1, q1[xg], s, 0, 0, 0);
            // lane holds w for p = ps + 4g + r (r=0..3), x = xb*64 + xg*16 + c
            f32x4 o;
            o[0] = __expf(s[0] * 0.125f) * inv[xg];
            o[1] = __expf(s[1] * 0.125f) * inv[xg];
            o[2] = __expf(s[2] * 0.125f) * inv[xg];
            o[3] = __expf(s[3] * 0.125f) * inv[xg];
            float* dst = w_out + ((size_t)(xb * 64 + xg * 16 + c) * NH + h) * NP + ps + g * 4;
            *(f32x4*)dst = o;
        }
    }
}

// ---------------------------------------------------------------------------
// K3: fc — per-head MFMA GEMM (2048 x 64out x 128k), relu, bf16 out
// ---------------------------------------------------------------------------
__global__ __launch_bounds__(256) void k_fc(const ushort_t* __restrict__ facat_b,
                                            const ushort_t* __restrict__ Wfc_b,
                                            const float* __restrict__ bfc,
                                            ushort_t* __restrict__ fcout_b) {
    int tid = threadIdx.x;
    int wv = tid >> 6, lane = tid & 63;
    int g = lane >> 4, c = lane & 15;
    int x0 = blockIdx.x * 64 + wv * 16;
    int h = blockIdx.y;

    const ushort_t* A = facat_b + ((size_t)h * NX + x0 + c) * 128 + g * 8;
    const ushort_t* B = Wfc_b + (size_t)h * FATT * 128;

    f32x4 acc[4] = {};
#pragma unroll
    for (int ks = 0; ks < 128; ks += 32) {
        frag_ab a = *(const frag_ab*)(A + ks);
#pragma unroll
        for (int t = 0; t < 4; ++t) {
            frag_ab b = *(const frag_ab*)(B + (size_t)(t * 16 + c) * 128 + ks + g * 8);
            acc[t] = __builtin_amdgcn_mfma_f32_16x16x32_bf16(a, b, acc[t], 0, 0, 0);
        }
    }
#pragma unroll
    for (int t = 0; t < 4; ++t) {
        int e = t * 16 + c;
        float bia = bfc[h * FATT + e];
#pragma unroll
        for (int r = 0; r < 4; ++r) {
            int x = x0 + g * 4 + r;
            fcout_b[(size_t)x * FDIM + h * FATT + e] = f2bf(fmaxf(acc[t][r] + bia, 0.f));
        }
    }
}

// ---------------------------------------------------------------------------
// K4: out GEMM (2048 x 512 x 512) MFMA + residual + bias + relu (fp32 out)
// ---------------------------------------------------------------------------
__global__ __launch_bounds__(256) void k_out(const float* __restrict__ fx_in,
                                             const ushort_t* __restrict__ fcout_b,
                                             const ushort_t* __restrict__ Wout_b,
                                             const float* __restrict__ bout,
                                             float* __restrict__ out) {
    int tid = threadIdx.x;
    int wv = tid >> 6, lane = tid & 63;
    int g = lane >> 4, c = lane & 15;
    int x0 = blockIdx.x * 64 + wv * 16;
    int o0 = blockIdx.y * 64;

    f32x4 acc[4] = {};
    const ushort_t* A = fcout_b + (size_t)(x0 + c) * FDIM + g * 8;
#pragma unroll 4
    for (int ks = 0; ks < FDIM; ks += 32) {
        frag_ab a = *(const frag_ab*)(A + ks);
#pragma unroll
        for (int t = 0; t < 4; ++t) {
            frag_ab b = *(const frag_ab*)(Wout_b + (size_t)(o0 + t * 16 + c) * FDIM + ks + g * 8);
            acc[t] = __builtin_amdgcn_mfma_f32_16x16x32_bf16(a, b, acc[t], 0, 0, 0);
        }
    }
#pragma unroll
    for (int t = 0; t < 4; ++t) {
        int f = o0 + t * 16 + c;
        float bia = bout[f];
#pragma unroll
        for (int r = 0; r < 4; ++r) {
            int x = x0 + g * 4 + r;
            float v = acc[t][r] + bia + fx_in[(size_t)x * FDIM + f];
            out[(size_t)x * FDIM + f] = fmaxf(v, 0.f);
        }
    }
}

extern "C" void kernel_launch(void* const* d_in, const int* in_sizes, int n_in,
                              void* d_out, int out_size, void* d_ws, size_t ws_size,
                              hipStream_t stream) {
    const float* fx_in = (const float*)d_in[0];
    const float* fp_in = (const float*)d_in[1];
    const float* Wembd = (const float*)d_in[2];
    const float* bembd = (const float*)d_in[3];
    const float* Wfc   = (const float*)d_in[4];
    const float* bfc   = (const float*)d_in[5];
    const float* Wout  = (const float*)d_in[6];
    const float* bout  = (const float*)d_in[7];

    float* out   = (float*)d_out;
    float* w_out = out + (size_t)NX * FDIM;

    ushort_t* f_b     = (ushort_t*)d_ws;                     // 6144*512
    ushort_t* We_b    = f_b + (size_t)NTOT * FDIM;           // 512*512
    ushort_t* femb_b  = We_b + (size_t)FDIM * FDIM;          // 8*6144*64
    ushort_t* fpT_b   = femb_b + (size_t)NH * NTOT * FATT;   // 8*64*4096
    ushort_t* facat_b = fpT_b + (size_t)NH * FATT * NP;      // 8*2048*128
    ushort_t* fcout_b = facat_b + (size_t)NH * NX * 128;     // 2048*512
    ushort_t* Wfc_b   = fcout_b + (size_t)NX * FDIM;         // 8*64*128
    ushort_t* Wout_b  = Wfc_b + (size_t)NH * FATT * 2 * FATT;// 512*512
    float*    inv_sums= (float*)(Wout_b + (size_t)FDIM * FDIM); // 8*2048 f32

    k_prep   <<<1024, 256, 0, stream>>>(fx_in, fp_in, Wembd, Wfc, Wout,
                                        f_b, We_b, Wfc_b, Wout_b);
    k_embed  <<<dim3(96, 8), 256, 0, stream>>>(f_b, We_b, bembd, femb_b, fpT_b, facat_b);
    k_attn_p1<<<256, 512, 0, stream>>>(femb_b, fpT_b, inv_sums, facat_b);
    k_wout   <<<2048, 256, 0, stream>>>(femb_b, inv_sums, w_out);
    k_fc     <<<dim3(32, 8), 256, 0, stream>>>(facat_b, Wfc_b, bfc, fcout_b);
    k_out    <<<dim3(32, 8), 256, 0, stream>>>(fx_in, fcout_b, Wout_b, bout, out);
}

// Round 20
// 174.814 us; speedup vs baseline: 1.1309x; 1.0253x over previous
//
#include <hip/hip_runtime.h>

typedef unsigned short ushort_t;
using frag_ab = __attribute__((ext_vector_type(8))) short;
using f32x4   = __attribute__((ext_vector_type(4))) float;
using u32x4   = __attribute__((ext_vector_type(4))) unsigned int;
using u32x2   = __attribute__((ext_vector_type(2))) unsigned int;

#define FDIM 512
#define NH 8
#define FATT 64
#define NX 2048
#define NP 4096
#define NTOT 6144

__device__ __forceinline__ ushort_t f2bf(float f) {
    unsigned u = __float_as_uint(f);
    u = (u + 0x7FFFu + ((u >> 16) & 1u)) >> 16;   // RTNE
    return (ushort_t)u;
}
__device__ __forceinline__ float bf2f(ushort_t s) {
    return __uint_as_float(((unsigned)s) << 16);
}
__device__ __forceinline__ unsigned pk2bf(float a, float b) {
    return (unsigned)f2bf(a) | ((unsigned)f2bf(b) << 16);
}

// ---------------------------------------------------------------------------
// K0: fp32 -> bf16 conversions: f = concat(fx, fp0), Wembd, Wfc, Wout
// ---------------------------------------------------------------------------
__global__ __launch_bounds__(256) void k_prep(const float* __restrict__ fx,
                                              const float* __restrict__ fp,
                                              const float* __restrict__ We,
                                              const float* __restrict__ Wfc,
                                              const float* __restrict__ Wout,
                                              ushort_t* __restrict__ f_b,
                                              ushort_t* __restrict__ We_b,
                                              ushort_t* __restrict__ Wfc_b,
                                              ushort_t* __restrict__ Wout_b) {
    int i = blockIdx.x * 256 + threadIdx.x;
    int stride = gridDim.x * 256;
    const int NF4 = NTOT * FDIM / 4;
    const int NX4 = NX * FDIM / 4;
    for (int idx = i; idx < NF4; idx += stride) {
        float4 v = (idx < NX4) ? ((const float4*)fx)[idx]
                               : ((const float4*)fp)[idx - NX4];
        ushort4 o;
        o.x = f2bf(v.x); o.y = f2bf(v.y); o.z = f2bf(v.z); o.w = f2bf(v.w);
        ((ushort4*)f_b)[idx] = o;
    }
    const int NW4 = FDIM * FDIM / 4;
    for (int idx = i; idx < NW4; idx += stride) {
        float4 v = ((const float4*)We)[idx];
        ushort4 o;
        o.x = f2bf(v.x); o.y = f2bf(v.y); o.z = f2bf(v.z); o.w = f2bf(v.w);
        ((ushort4*)We_b)[idx] = o;
    }
    const int NFC4 = NH * FATT * 2 * FATT / 4;
    for (int idx = i; idx < NFC4; idx += stride) {
        float4 v = ((const float4*)Wfc)[idx];
        ushort4 o;
        o.x = f2bf(v.x); o.y = f2bf(v.y); o.z = f2bf(v.z); o.w = f2bf(v.w);
        ((ushort4*)Wfc_b)[idx] = o;
    }
    for (int idx = i; idx < NW4; idx += stride) {
        float4 v = ((const float4*)Wout)[idx];
        ushort4 o;
        o.x = f2bf(v.x); o.y = f2bf(v.y); o.z = f2bf(v.z); o.w = f2bf(v.w);
        ((ushort4*)Wout_b)[idx] = o;
    }
}

// ---------------------------------------------------------------------------
// K1: femb[h][n][e] = f[n] . Wembd[h][e] + bembd  (MFMA GEMM, bf16 out)
//     also writes fpT[h][e][p] (n>=NX) and facat[h][x][64+e] (n<NX)
// ---------------------------------------------------------------------------
__global__ __launch_bounds__(256) void k_embed(const ushort_t* __restrict__ f_b,
                                               const ushort_t* __restrict__ We_b,
                                               const float* __restrict__ bembd,
                                               ushort_t* __restrict__ femb_b,
                                               ushort_t* __restrict__ fpT_b,
                                               ushort_t* __restrict__ facat_b) {
    int tid = threadIdx.x;
    int wv = tid >> 6, lane = tid & 63;
    int g = lane >> 4, c = lane & 15;
    int m0 = blockIdx.x * 64 + wv * 16;
    int o0 = blockIdx.y * 64;

    f32x4 acc[4] = {};
    const ushort_t* arow = f_b + (size_t)(m0 + c) * FDIM + g * 8;
#pragma unroll 4
    for (int ks = 0; ks < FDIM; ks += 32) {
        frag_ab a = *(const frag_ab*)(arow + ks);
#pragma unroll
        for (int t = 0; t < 4; ++t) {
            const ushort_t* brow = We_b + (size_t)(o0 + t * 16 + c) * FDIM + ks + g * 8;
            frag_ab b = *(const frag_ab*)brow;
            acc[t] = __builtin_amdgcn_mfma_f32_16x16x32_bf16(a, b, acc[t], 0, 0, 0);
        }
    }
#pragma unroll
    for (int t = 0; t < 4; ++t) {
        int o = o0 + t * 16 + c;           // output feature = h*64+e
        int h = o >> 6, e = o & 63;
        float bia = bembd[o];
#pragma unroll
        for (int r = 0; r < 4; ++r) {
            int n = m0 + g * 4 + r;
            ushort_t v = f2bf(acc[t][r] + bia);
            femb_b[((size_t)h * NTOT + n) * FATT + e] = v;
            if (n >= NX) fpT_b[((size_t)h * FATT + e) * NP + (n - NX)] = v;
            else         facat_b[((size_t)h * NX + n) * 128 + 64 + e] = v;
        }
    }
}

// ---------------------------------------------------------------------------
// K2a: attention pass-1 (round-17 validated best) — 512 threads (8 waves),
//   64 x-rows/block, wave owns a 512-p slice. K/V reads amortized over 64 x.
//   Writes facat bf16 + inv_sums.
// ---------------------------------------------------------------------------
__global__ __launch_bounds__(512) void k_attn_p1(const ushort_t* __restrict__ femb_b,
                                                 const ushort_t* __restrict__ fpT_b,
                                                 float* __restrict__ inv_sums,
                                                 ushort_t* __restrict__ facat_b) {
    int bid = blockIdx.x;
    int h  = bid & 7;                 // head == XCD affinity
    int xb = bid >> 3;                // 0..31, x-base = xb*64
    int tid = threadIdx.x;
    int wv = tid >> 6;                // 0..7 -> 512-p slice
    int lane = tid & 63;
    int g = lane >> 4, c = lane & 15;

    __shared__ float lds_pv[64][68];  // combined PV [x_local][e], pad 68
    __shared__ float lds_sum[64];
    __shared__ float lds_inv[64];

    const ushort_t* fxb = femb_b + (size_t)h * NTOT * FATT;
    const ushort_t* fpb = fxb + (size_t)NX * FATT;
    const ushort_t* fTb = fpT_b + (size_t)h * FATT * NP;

    // Q B-frags for 4 x-groups
    frag_ab bx0_0, bx0_1, bx1_0, bx1_1, bx2_0, bx2_1, bx3_0, bx3_1;
    {
        const ushort_t* b0 = fxb + (size_t)(xb * 64 + 0 * 16 + c) * FATT + g * 8;
        const ushort_t* b1 = fxb + (size_t)(xb * 64 + 1 * 16 + c) * FATT + g * 8;
        const ushort_t* b2 = fxb + (size_t)(xb * 64 + 2 * 16 + c) * FATT + g * 8;
        const ushort_t* b3 = fxb + (size_t)(xb * 64 + 3 * 16 + c) * FATT + g * 8;
        bx0_0 = *(const frag_ab*)b0;  bx0_1 = *(const frag_ab*)(b0 + 32);
        bx1_0 = *(const frag_ab*)b1;  bx1_1 = *(const frag_ab*)(b1 + 32);
        bx2_0 = *(const frag_ab*)b2;  bx2_1 = *(const frag_ab*)(b2 + 32);
        bx3_0 = *(const frag_ab*)b3;  bx3_1 = *(const frag_ab*)(b3 + 32);
    }

    f32x4 pacc[4][4] = {};            // [xg][t2], static indices only
    float rsum[4] = {0.f, 0.f, 0.f, 0.f};
    const int p0 = wv * 512;

    for (int ps = p0; ps < p0 + 512; ps += 16) {
        const ushort_t* ar = fpb + (size_t)(ps + c) * FATT + g * 8;
        frag_ab a0 = *(const frag_ab*)ar;
        frag_ab a1 = *(const frag_ab*)(ar + 32);
        frag_ab pb[4];
#pragma unroll
        for (int xg = 0; xg < 4; ++xg) {
            frag_ab q0 = (xg == 0) ? bx0_0 : (xg == 1) ? bx1_0 : (xg == 2) ? bx2_0 : bx3_0;
            frag_ab q1 = (xg == 0) ? bx0_1 : (xg == 1) ? bx1_1 : (xg == 2) ? bx2_1 : bx3_1;
            f32x4 s = {};
            s = __builtin_amdgcn_mfma_f32_16x16x32_bf16(a0, q0, s, 0, 0, 0);
            s = __builtin_amdgcn_mfma_f32_16x16x32_bf16(a1, q1, s, 0, 0, 0);
            float e0 = __expf(s[0] * 0.125f);
            float e1 = __expf(s[1] * 0.125f);
            float e2 = __expf(s[2] * 0.125f);
            float e3 = __expf(s[3] * 0.125f);
            rsum[xg] += (e0 + e1) + (e2 + e3);
            u32x4 bw;
            bw[0] = pk2bf(e0, e1);
            bw[1] = pk2bf(e2, e3);
            bw[2] = 0u;
            bw[3] = 0u;
            pb[xg] = __builtin_bit_cast(frag_ab, bw);
        }
#pragma unroll
        for (int t2 = 0; t2 < 4; ++t2) {
            const ushort_t* vr = fTb + (size_t)(t2 * 16 + c) * NP + ps + g * 4;
            u32x2 vl = *(const u32x2*)vr;
            u32x4 aw;
            aw[0] = vl[0];
            aw[1] = vl[1];
            aw[2] = 0u;
            aw[3] = 0u;
            frag_ab va = __builtin_bit_cast(frag_ab, aw);
#pragma unroll
            for (int xg = 0; xg < 4; ++xg)
                pacc[xg][t2] = __builtin_amdgcn_mfma_f32_16x16x32_bf16(va, pb[xg], pacc[xg][t2], 0, 0, 0);
        }
    }

#pragma unroll
    for (int xg = 0; xg < 4; ++xg) {
        rsum[xg] += __shfl_xor(rsum[xg], 16);
        rsum[xg] += __shfl_xor(rsum[xg], 32);
    }

    // cross-wave combine: 8 serialized accumulation rounds
    for (int w = 0; w < 8; ++w) {
        if (wv == w) {
            if (w == 0) {
                if (lane < 16) {
#pragma unroll
                    for (int xg = 0; xg < 4; ++xg) lds_sum[xg * 16 + c] = rsum[xg];
                }
#pragma unroll
                for (int xg = 0; xg < 4; ++xg)
#pragma unroll
                    for (int t2 = 0; t2 < 4; ++t2)
                        *(f32x4*)&lds_pv[xg * 16 + c][t2 * 16 + 4 * g] = pacc[xg][t2];
            } else {
                if (lane < 16) {
#pragma unroll
                    for (int xg = 0; xg < 4; ++xg) lds_sum[xg * 16 + c] += rsum[xg];
                }
#pragma unroll
                for (int xg = 0; xg < 4; ++xg)
#pragma unroll
                    for (int t2 = 0; t2 < 4; ++t2) {
                        f32x4 cur = *(const f32x4*)&lds_pv[xg * 16 + c][t2 * 16 + 4 * g];
                        cur += pacc[xg][t2];
                        *(f32x4*)&lds_pv[xg * 16 + c][t2 * 16 + 4 * g] = cur;
                    }
            }
        }
        __syncthreads();
    }
    if (tid < 64) {
        float inv = 1.f / lds_sum[tid];
        lds_inv[tid] = inv;
        inv_sums[(size_t)h * NX + xb * 64 + tid] = inv;
    }
    __syncthreads();

    // facat write: 512 threads x 8 elems = 64 x-rows x 64 e
    {
        int row = tid >> 3;
        int e0 = (tid & 7) * 8;
        float inv = lds_inv[row];
        u32x4 o;
#pragma unroll
        for (int j = 0; j < 4; ++j)
            o[j] = pk2bf(lds_pv[row][e0 + 2 * j] * inv, lds_pv[row][e0 + 2 * j + 1] * inv);
        *(u32x4*)&facat_b[((size_t)h * NX + xb * 64 + row) * 128 + e0] = o;
    }
}

// ---------------------------------------------------------------------------
// K2b: w_out writer v4 — 128-x read amortization (8 Q-groups per A-read,
//   pt-outer/xg-inner, transient A registers). No LDS, no barriers; direct
//   f32x4 stores (1 KB/instruction per wave). Grid 1024 = 8h x 16xb x 8sl;
//   4 waves, wave owns 128 x times 128 p.
// ---------------------------------------------------------------------------
__global__ __launch_bounds__(256) void k_wout(const ushort_t* __restrict__ femb_b,
                                              const float* __restrict__ inv_sums,
                                              float* __restrict__ w_out) {
    int bid = blockIdx.x;
    int h    = bid & 7;
    int rest = bid >> 3;               // 0..127
    int xb   = rest & 15;              // 128-x group
    int sl   = rest >> 4;              // 0..7 -> 512-p slice
    int tid = threadIdx.x;
    int wv = tid >> 6;                 // 0..3 -> 128-p sub-slice
    int lane = tid & 63;
    int g = lane >> 4, c = lane & 15;

    const ushort_t* fxb = femb_b + (size_t)h * NTOT * FATT;
    const ushort_t* fpb = fxb + (size_t)NX * FATT;

    // Q frags + inv for 8 x-groups (x = xb*128 + xg*16 + c)
    frag_ab q0[8], q1[8];
    float inv[8];
#pragma unroll
    for (int xg = 0; xg < 8; ++xg) {
        const ushort_t* b = fxb + (size_t)(xb * 128 + xg * 16 + c) * FATT + g * 8;
        q0[xg] = *(const frag_ab*)b;
        q1[xg] = *(const frag_ab*)(b + 32);
        inv[xg] = inv_sums[(size_t)h * NX + xb * 128 + xg * 16 + c];
    }

    const int p0 = sl * 512 + wv * 128;
    for (int ps = p0; ps < p0 + 128; ps += 16) {
        // read the A-fragment pair ONCE, reuse for 8 x-groups (128 x)
        const ushort_t* ar = fpb + (size_t)(ps + c) * FATT + g * 8;
        frag_ab a0 = *(const frag_ab*)ar;
        frag_ab a1 = *(const frag_ab*)(ar + 32);
#pragma unroll
        for (int xg = 0; xg < 8; ++xg) {
            f32x4 s = {};
            s = __builtin_amdgcn_mfma_f32_16x16x32_bf16(a0, q0[xg], s, 0, 0, 0);
            s = __builtin_amdgcn_mfma_f32_16x16x32_bf16(a1, q1[xg], s, 0, 0, 0);
            // lane holds w for p = ps + 4g + r (r=0..3), x = xb*128 + xg*16 + c
            f32x4 o;
            o[0] = __expf(s[0] * 0.125f) * inv[xg];
            o[1] = __expf(s[1] * 0.125f) * inv[xg];
            o[2] = __expf(s[2] * 0.125f) * inv[xg];
            o[3] = __expf(s[3] * 0.125f) * inv[xg];
            float* dst = w_out + ((size_t)(xb * 128 + xg * 16 + c) * NH + h) * NP + ps + g * 4;
            *(f32x4*)dst = o;
        }
    }
}

// ---------------------------------------------------------------------------
// K3: fc — per-head MFMA GEMM (2048 x 64out x 128k), relu, bf16 out
// ---------------------------------------------------------------------------
__global__ __launch_bounds__(256) void k_fc(const ushort_t* __restrict__ facat_b,
                                            const ushort_t* __restrict__ Wfc_b,
                                            const float* __restrict__ bfc,
                                            ushort_t* __restrict__ fcout_b) {
    int tid = threadIdx.x;
    int wv = tid >> 6, lane = tid & 63;
    int g = lane >> 4, c = lane & 15;
    int x0 = blockIdx.x * 64 + wv * 16;
    int h = blockIdx.y;

    const ushort_t* A = facat_b + ((size_t)h * NX + x0 + c) * 128 + g * 8;
    const ushort_t* B = Wfc_b + (size_t)h * FATT * 128;

    f32x4 acc[4] = {};
#pragma unroll
    for (int ks = 0; ks < 128; ks += 32) {
        frag_ab a = *(const frag_ab*)(A + ks);
#pragma unroll
        for (int t = 0; t < 4; ++t) {
            frag_ab b = *(const frag_ab*)(B + (size_t)(t * 16 + c) * 128 + ks + g * 8);
            acc[t] = __builtin_amdgcn_mfma_f32_16x16x32_bf16(a, b, acc[t], 0, 0, 0);
        }
    }
#pragma unroll
    for (int t = 0; t < 4; ++t) {
        int e = t * 16 + c;
        float bia = bfc[h * FATT + e];
#pragma unroll
        for (int r = 0; r < 4; ++r) {
            int x = x0 + g * 4 + r;
            fcout_b[(size_t)x * FDIM + h * FATT + e] = f2bf(fmaxf(acc[t][r] + bia, 0.f));
        }
    }
}

// ---------------------------------------------------------------------------
// K4: out GEMM (2048 x 512 x 512) MFMA + residual + bias + relu (fp32 out)
// ---------------------------------------------------------------------------
__global__ __launch_bounds__(256) void k_out(const float* __restrict__ fx_in,
                                             const ushort_t* __restrict__ fcout_b,
                                             const ushort_t* __restrict__ Wout_b,
                                             const float* __restrict__ bout,
                                             float* __restrict__ out) {
    int tid = threadIdx.x;
    int wv = tid >> 6, lane = tid & 63;
    int g = lane >> 4, c = lane & 15;
    int x0 = blockIdx.x * 64 + wv * 16;
    int o0 = blockIdx.y * 64;

    f32x4 acc[4] = {};
    const ushort_t* A = fcout_b + (size_t)(x0 + c) * FDIM + g * 8;
#pragma unroll 4
    for (int ks = 0; ks < FDIM; ks += 32) {
        frag_ab a = *(const frag_ab*)(A + ks);
#pragma unroll
        for (int t = 0; t < 4; ++t) {
            frag_ab b = *(const frag_ab*)(Wout_b + (size_t)(o0 + t * 16 + c) * FDIM + ks + g * 8);
            acc[t] = __builtin_amdgcn_mfma_f32_16x16x32_bf16(a, b, acc[t], 0, 0, 0);
        }
    }
#pragma unroll
    for (int t = 0; t < 4; ++t) {
        int f = o0 + t * 16 + c;
        float bia = bout[f];
#pragma unroll
        for (int r = 0; r < 4; ++r) {
            int x = x0 + g * 4 + r;
            float v = acc[t][r] + bia + fx_in[(size_t)x * FDIM + f];
            out[(size_t)x * FDIM + f] = fmaxf(v, 0.f);
        }
    }
}

extern "C" void kernel_launch(void* const* d_in, const int* in_sizes, int n_in,
                              void* d_out, int out_size, void* d_ws, size_t ws_size,
                              hipStream_t stream) {
    const float* fx_in = (const float*)d_in[0];
    const float* fp_in = (const float*)d_in[1];
    const float* Wembd = (const float*)d_in[2];
    const float* bembd = (const float*)d_in[3];
    const float* Wfc   = (const float*)d_in[4];
    const float* bfc   = (const float*)d_in[5];
    const float* Wout  = (const float*)d_in[6];
    const float* bout  = (const float*)d_in[7];

    float* out   = (float*)d_out;
    float* w_out = out + (size_t)NX * FDIM;

    ushort_t* f_b     = (ushort_t*)d_ws;                     // 6144*512
    ushort_t* We_b    = f_b + (size_t)NTOT * FDIM;           // 512*512
    ushort_t* femb_b  = We_b + (size_t)FDIM * FDIM;          // 8*6144*64
    ushort_t* fpT_b   = femb_b + (size_t)NH * NTOT * FATT;   // 8*64*4096
    ushort_t* facat_b = fpT_b + (size_t)NH * FATT * NP;      // 8*2048*128
    ushort_t* fcout_b = facat_b + (size_t)NH * NX * 128;     // 2048*512
    ushort_t* Wfc_b   = fcout_b + (size_t)NX * FDIM;         // 8*64*128
    ushort_t* Wout_b  = Wfc_b + (size_t)NH * FATT * 2 * FATT;// 512*512
    float*    inv_sums= (float*)(Wout_b + (size_t)FDIM * FDIM); // 8*2048 f32

    k_prep   <<<1024, 256, 0, stream>>>(fx_in, fp_in, Wembd, Wfc, Wout,
                                        f_b, We_b, Wfc_b, Wout_b);
    k_embed  <<<dim3(96, 8), 256, 0, stream>>>(f_b, We_b, bembd, femb_b, fpT_b, facat_b);
    k_attn_p1<<<256, 512, 0, stream>>>(femb_b, fpT_b, inv_sums, facat_b);
    k_wout   <<<1024, 256, 0, stream>>>(femb_b, inv_sums, w_out);
    k_fc     <<<dim3(32, 8), 256, 0, stream>>>(facat_b, Wfc_b, bfc, fcout_b);
    k_out    <<<dim3(32, 8), 256, 0, stream>>>(fx_in, fcout_b, Wout_b, bout, out);
}